// Round 1
// baseline (304.856 us; speedup 1.0000x reference)
//
#include <hip/hip_runtime.h>

// ---------- types ----------
typedef __attribute__((ext_vector_type(8))) short short8;     // 8 bf16 (4 VGPRs)
typedef __attribute__((ext_vector_type(4))) float floatx4;    // MFMA C/D
typedef __attribute__((ext_vector_type(4))) unsigned int uintx4;

// ---------- fp32 -> packed bf16x2 (RNE) ----------
#if __has_builtin(__builtin_amdgcn_cvt_pk_bf16_f32)
typedef __attribute__((ext_vector_type(2))) __bf16 bf16x2;
__device__ __forceinline__ unsigned int pk_bf16(float a, float b) {
  bf16x2 v = __builtin_amdgcn_cvt_pk_bf16_f32(a, b);
  return __builtin_bit_cast(unsigned int, v);
}
#else
__device__ __forceinline__ unsigned int bf16_1(float f) {
  unsigned int u = __builtin_bit_cast(unsigned int, f);
  return (u + 0x7fffu + ((u >> 16) & 1u)) >> 16;
}
__device__ __forceinline__ unsigned int pk_bf16(float a, float b) {
  return bf16_1(a) | (bf16_1(b) << 16);
}
#endif

// ---------- async global->LDS, 16B per lane ----------
__device__ __forceinline__ void gload_lds16(const void* g, void* l) {
  __builtin_amdgcn_global_load_lds((const __attribute__((address_space(1))) void*)g,
                                   (__attribute__((address_space(3))) void*)l,
                                   16, 0, 0);
}

// ============================================================
// Prepass: W [8][64][768] fp32  ->  bf16 B-fragments in MFMA lane order.
// Frag (mod, n16 in [0,32), ks in [0,24)): 64 lanes x 16B; lane l holds
// B[k = ks*32 + (l>>4)*8 + jj][n = n16*16 + (l&15)], jj=0..7, where
// B[k][n] = W[c][r][k], n = r*8 + c.
// Also biasPrep[mod*512 + n] = b[c*64 + r].
// ============================================================
__global__ __launch_bounds__(256) void prep_kernel(
    const float* __restrict__ Wi, const float* __restrict__ Wc, const float* __restrict__ Wd,
    const float* __restrict__ bi, const float* __restrict__ bc, const float* __restrict__ bd,
    unsigned int* __restrict__ Bprep, float* __restrict__ biasPrep) {
  const int t = blockIdx.x * 256 + threadIdx.x;  // 0 .. 147455
  const int l = t & 63;
  const int frag = t >> 6;              // 0 .. 2303
  const int mod = frag / 768;           // 32*24 frags per modality
  const int rem = frag - mod * 768;
  const int n16 = rem / 24;
  const int ks = rem - n16 * 24;
  const float* __restrict__ W = (mod == 0) ? Wi : ((mod == 1) ? Wc : Wd);

  const int n = n16 * 16 + (l & 15);
  const int r = n >> 3;
  const int c = n & 7;
  const int i0 = ks * 32 + (l >> 4) * 8;
  const float* src = W + (size_t)(c * 64 + r) * 768 + i0;
  float4 f0 = *(const float4*)(src);
  float4 f1 = *(const float4*)(src + 4);
  uintx4 p;
  p.x = pk_bf16(f0.x, f0.y);
  p.y = pk_bf16(f0.z, f0.w);
  p.z = pk_bf16(f1.x, f1.y);
  p.w = pk_bf16(f1.z, f1.w);
  ((uintx4*)Bprep)[frag * 64 + l] = p;

  if (t < 1536) {
    const int m2 = t >> 9;
    const int nn = t & 511;
    const float* bb = (m2 == 0) ? bi : ((m2 == 1) ? bc : bd);
    biasPrep[t] = bb[(nn & 7) * 64 + (nn >> 3)];
  }
}

// ============================================================
// Fused projection + squash.
// Grid: 1536 blocks = 3 mods x 128 m-tiles x 4 n-tiles (n fastest for A reuse).
// Block: 256 thr = 4 waves; wave (wm,wn) covers 64x64; 4x4 frags of 16x16x32.
// A (x, fp32) staged to LDS via global_load_lds with XOR chunk swizzle:
//   chunk (row, kg) of 4 floats lives at slot row*8 + (kg ^ (row&7)).
// B frags loaded straight from pre-swizzled Bprep (L2-resident).
// ============================================================
__global__ __launch_bounds__(256) void caps_gemm(
    const float* __restrict__ x0, const float* __restrict__ x1, const float* __restrict__ x2,
    const uintx4* __restrict__ Bprep, const float* __restrict__ biasPrep,
    float* __restrict__ out) {
  __shared__ float As[4096];  // 128 rows x 32 floats, swizzled, 16 KB

  const int tid = threadIdx.x;
  const int bx = blockIdx.x;
  const int mod = bx >> 9;
  const int tt = bx & 511;
  const int bm = tt >> 2;
  const int bn = tt & 3;
  const float* __restrict__ X = (mod == 0) ? x0 : ((mod == 1) ? x1 : x2);

  const int wid = tid >> 6;
  const int lane = tid & 63;
  const int ln = lane & 15;
  const int l7 = ln & 7;
  const int quad = lane >> 4;
  const int wm = wid & 1;
  const int wn = wid >> 1;

  // --- staging addresses (thread -> global chunk; LDS dest is implicit base+lane*16)
  const int rowT = tid >> 3;                       // 0..31 (+p*32)
  const int kgT = (tid & 7) ^ (rowT & 7);          // un-swizzled k-group
  const float* gA = X + (size_t)(bm * 128 + rowT) * 768 + kgT * 4;
  float* ldsW = As + wid * 256;                    // +p*1024 floats

  // --- A fragment LDS offsets (floats), constant across K-steps
  const int arow0 = (wm * 64 + ln) * 32;
  const int aoff0 = (((quad * 2 + 0) ^ l7) * 4);
  const int aoff1 = (((quad * 2 + 1) ^ l7) * 4);

  // --- B fragment pointer
  const uintx4* bptr = Bprep + (size_t)((mod * 32 + bn * 8 + wn * 4) * 24) * 64 + lane;

  floatx4 acc[4][4] = {};

  for (int ks = 0; ks < 24; ++ks) {
    const float* g = gA + ks * 32;
#pragma unroll
    for (int p = 0; p < 4; ++p)
      gload_lds16(g + (size_t)p * 32 * 768, ldsW + p * 1024);
    __syncthreads();  // drains vmcnt -> LDS tile visible

    uintx4 bf[4];
#pragma unroll
    for (int j = 0; j < 4; ++j) bf[j] = bptr[(size_t)j * (24 * 64) + ks * 64];

#pragma unroll
    for (int mt = 0; mt < 4; ++mt) {
      const float* ar = As + arow0 + mt * 512;
      float4 a0 = *(const float4*)(ar + aoff0);
      float4 a1 = *(const float4*)(ar + aoff1);
      uintx4 pa;
      pa.x = pk_bf16(a0.x, a0.y);
      pa.y = pk_bf16(a0.z, a0.w);
      pa.z = pk_bf16(a1.x, a1.y);
      pa.w = pk_bf16(a1.z, a1.w);
      short8 af = __builtin_bit_cast(short8, pa);
#pragma unroll
      for (int nt = 0; nt < 4; ++nt)
        acc[mt][nt] = __builtin_amdgcn_mfma_f32_16x16x32_bf16(
            af, __builtin_bit_cast(short8, bf[nt]), acc[mt][nt], 0, 0, 0);
    }
    __syncthreads();  // protect LDS before next stage
  }

  // --- epilogue: bias + squash (sum over 8 consecutive n = 8 lanes) + store
  const int nb = mod * 512 + bn * 128 + wn * 64 + ln;  // absolute out column
  float bias[4];
#pragma unroll
  for (int nt = 0; nt < 4; ++nt) bias[nt] = biasPrep[nb + nt * 16];

  const int mrow0 = bm * 128 + wm * 64 + quad * 4;
#pragma unroll
  for (int mt = 0; mt < 4; ++mt) {
    const size_t rbase = (size_t)(mrow0 + mt * 16) * 1536;
#pragma unroll
    for (int nt = 0; nt < 4; ++nt) {
      float* op = out + rbase + nb + nt * 16;
#pragma unroll
      for (int j = 0; j < 4; ++j) {
        float u = acc[mt][nt][j] + bias[nt];
        float s = u * u;
        s += __shfl_xor(s, 1);
        s += __shfl_xor(s, 2);
        s += __shfl_xor(s, 4);
        float sc = s / ((1.0f + s) * sqrtf(s + 1e-7f));
        op[(size_t)j * 1536] = u * sc;
      }
    }
  }
}

// ============================================================
extern "C" void kernel_launch(void* const* d_in, const int* in_sizes, int n_in,
                              void* d_out, int out_size, void* d_ws, size_t ws_size,
                              hipStream_t stream) {
  const float* ximg = (const float*)d_in[0];
  const float* xcapt = (const float*)d_in[1];
  const float* xdct = (const float*)d_in[2];
  const float* Wi = (const float*)d_in[3];
  const float* bi = (const float*)d_in[4];
  const float* Wc = (const float*)d_in[5];
  const float* bc = (const float*)d_in[6];
  const float* Wd = (const float*)d_in[7];
  const float* bd = (const float*)d_in[8];

  unsigned int* Bprep = (unsigned int*)d_ws;                 // 2304 KiB
  float* biasPrep = (float*)((char*)d_ws + 2304 * 1024);     // 6 KiB

  hipLaunchKernelGGL(prep_kernel, dim3(576), dim3(256), 0, stream,
                     Wi, Wc, Wd, bi, bc, bd, Bprep, biasPrep);
  hipLaunchKernelGGL(caps_gemm, dim3(1536), dim3(256), 0, stream,
                     ximg, xcapt, xdct, (const uintx4*)Bprep, biasPrep, (float*)d_out);
}